// Round 1
// 279.293 us; speedup vs baseline: 1.0017x; 1.0017x over previous
//
#include <hip/hip_runtime.h>
#include <hip/hip_bf16.h>

#define B_DIM 16
#define C_DIM 256
#define E_DIM 9216
#define K_DIM 4096
#define SEL_T 512              // select block threads
#define EPT   (E_DIM / SEL_T)  // 18 keys per thread, contiguous

typedef float v4f __attribute__((ext_vector_type(4)));

// ---------------------------------------------------------------------------
// Kernel 1: score[b,e] = sum_c x[b,c,e]^2 -> sortable uint key.
// Non-negative floats: bits | 0x80000000 is order-preserving. Invalid edges
// get key 0. Double accumulation => correctly-rounded fp32 score (immune to
// reduction-order differences vs XLA at the top-K boundary).
//
// Launch geometry v2: 256-thread blocks; each block owns 64 edges, and each
// of its 4 waves covers a 64-channel slice of those edges. This keeps the
// per-c access perfectly coalesced (64 consecutive e per wave-load) while
// raising occupancy from 9 waves/CU (2.25/SIMD — latency-hiding relied
// entirely on per-thread ILP) to the 32 waves/CU cap, and cutting the
// per-thread vmcnt dependency chain from 256 to 64 loads. Partial sums are
// combined in DOUBLE via LDS and rounded to f32 exactly once, so keys are
// bit-identical to the single-thread-per-edge version.
// ---------------------------------------------------------------------------
__global__ __launch_bounds__(256) void score_kernel(
    const float* __restrict__ x, const void* __restrict__ ecp,
    unsigned* __restrict__ keys) {
  __shared__ double part[3][64];  // waves 1..3 deposit partials

  const int lane = threadIdx.x & 63;
  const int w = threadIdx.x >> 6;           // wave id 0..3 -> c-slice
  const int blk = blockIdx.x;               // 0 .. B*E/64-1  (2304)
  const int b = blk / (E_DIM / 64);         // 144 blocks per mesh
  const int e = (blk % (E_DIM / 64)) * 64 + lane;

  const float* col =
      x + (size_t)b * C_DIM * E_DIM + (size_t)(w * 64) * E_DIM + e;

  double a0 = 0.0, a1 = 0.0;
#pragma unroll 8
  for (int c = 0; c < 64; c += 2) {
    float v0 = col[(size_t)(c + 0) * E_DIM];
    float v1 = col[(size_t)(c + 1) * E_DIM];
    a0 += (double)v0 * v0;
    a1 += (double)v1 * v1;
  }
  double s = a0 + a1;

  if (w) part[w - 1][lane] = s;
  __syncthreads();

  if (w == 0) {
    s += part[0][lane] + (part[1][lane] + part[2][lane]);

    // edges_count dtype sniff: counts are in [K, E] (fit in 16 bits), so an
    // int64 little-endian layout has zero at odd int32 positions.
    const int* p32 = (const int*)ecp;
    long long cnt =
        (p32[1] == 0) ? ((const long long*)ecp)[b] : (long long)p32[b];

    float f = (float)s;
    keys[(size_t)b * E_DIM + (blk % (E_DIM / 64)) * 64 + lane] =
        (e < cnt) ? (__float_as_uint(f) | 0x80000000u) : 0u;
  }
}

// ---------------------------------------------------------------------------
// Block-wide exclusive scan over SEL_T threads (8 waves). Returns excl + tot.
// ---------------------------------------------------------------------------
__device__ __forceinline__ void block_scan(int val, int tid, int* wsum,
                                           int* excl, int* total) {
  int lane = tid & 63;
  int wid = tid >> 6;
  int v = val;
#pragma unroll
  for (int i = 1; i < 64; i <<= 1) {
    int t = __shfl_up(v, i, 64);
    if (lane >= i) v += t;
  }
  if (lane == 63) wsum[wid] = v;
  __syncthreads();
  int base = 0, tot = 0;
#pragma unroll
  for (int w = 0; w < SEL_T / 64; w++) {
    int s = wsum[w];
    if (w < wid) base += s;
    tot += s;
  }
  *excl = base + v - val;
  *total = tot;
  __syncthreads();
}

// ---------------------------------------------------------------------------
// Kernel 2: one block per mesh. 4-pass MSB radix select.
//  - keys held in registers, EPT contiguous per thread
//  - histogram via ballot-match (one leader atomic per distinct byte per
//    wave -> no same-bin serialization even with clustered exponents)
//  - boundary bin found by parallel suffix-scan over 256 bins
//  - compaction with ONE packed block scan, emits ascending-e order:
//    all key>T plus first need_eq key==T  == sort(top_k(score,K).indices)
// ---------------------------------------------------------------------------
__global__ __launch_bounds__(SEL_T) void select_kernel(
    const unsigned* __restrict__ keys, int* __restrict__ keep) {
  __shared__ unsigned lkeys[E_DIM];
  __shared__ int hist[256];
  __shared__ int wsum[SEL_T / 64];
  __shared__ unsigned sh_prefix;
  __shared__ int sh_remK;

  const int b = blockIdx.x;
  const int tid = threadIdx.x;
  const int lane = tid & 63;

  // stage keys (coalesced uint2), then pull contiguous EPT into registers
  {
    const uint2* gk = (const uint2*)(keys + (size_t)b * E_DIM);
    uint2* lk2 = (uint2*)lkeys;
    for (int i = tid; i < E_DIM / 2; i += SEL_T) lk2[i] = gk[i];
  }
  __syncthreads();

  unsigned kreg[EPT];
  const int base_e = tid * EPT;
#pragma unroll
  for (int j = 0; j < EPT; j++) kreg[j] = lkeys[base_e + j];

  unsigned prefix = 0;
  int remK = K_DIM;
#pragma unroll
  for (int pass = 3; pass >= 0; pass--) {
    const int shift = pass * 8;
    if (tid < 256) hist[tid] = 0;
    __syncthreads();

    // ballot-match histogram
#pragma unroll
    for (int j = 0; j < EPT; j++) {
      unsigned key = kreg[j];
      bool cand = (pass == 3) || ((key >> (shift + 8)) == prefix);
      unsigned byte = (key >> shift) & 255u;
      unsigned long long m = __ballot(cand);
#pragma unroll
      for (int bit = 0; bit < 8; bit++) {
        unsigned long long bb = __ballot((byte >> bit) & 1u);
        m &= ((byte >> bit) & 1u) ? bb : ~bb;
      }
      if (cand) {
        int leader = __ffsll((unsigned long long)m) - 1;
        if (lane == leader) atomicAdd(&hist[byte], (int)__popcll(m));
      }
    }
    __syncthreads();

    // parallel suffix count: thread tid<256 handles bin u = 255-tid
    int h = 0;
    if (tid < 256) h = hist[255 - tid];
    int excl, tot;
    block_scan(h, tid, wsum, &excl, &tot);
    if (tid < 256) {
      int s_incl = excl + h;  // suffix[u] = sum of bins >= u
      if (s_incl >= remK && (s_incl - h) < remK) {
        sh_prefix = (prefix << 8) | (unsigned)(255 - tid);
        sh_remK = remK - (s_incl - h);
      }
    }
    __syncthreads();
    prefix = sh_prefix;
    remK = sh_remK;
  }

  const unsigned T = prefix;
  const int need_eq = remK;

  // compaction: one packed scan (gt<<16 | eq), then per-thread ordered emit
  int gt_cnt = 0, eq_cnt = 0;
#pragma unroll
  for (int j = 0; j < EPT; j++) {
    gt_cnt += (kreg[j] > T);
    eq_cnt += (kreg[j] == T);
  }
  int excl, tot;
  block_scan((gt_cnt << 16) | eq_cnt, tid, wsum, &excl, &tot);
  int gt_b = excl >> 16;
  int eq_b = excl & 0xFFFF;

  int* kout = keep + b * K_DIM;
#pragma unroll
  for (int j = 0; j < EPT; j++) {
    unsigned key = kreg[j];
    if (key > T) {
      int pos = gt_b + (eq_b < need_eq ? eq_b : need_eq);
      kout[pos] = base_e + j;
      gt_b++;
    } else if (key == T) {
      if (eq_b < need_eq) kout[gt_b + eq_b] = base_e + j;
      eq_b++;
    }
  }
}

// ---------------------------------------------------------------------------
// Kernel 3: gather. 4 outputs per thread (float4 store, int4 index load).
// Ascending indices -> high L1/L2/L3 locality on the reads. The 64 MB output
// is never re-read: non-temporal stores keep it from evicting x (151 MB)
// from the 256 MB Infinity Cache, so gather reads stay L3-served.
// ---------------------------------------------------------------------------
__global__ __launch_bounds__(256) void gather_kernel(
    const float* __restrict__ x, const int* __restrict__ keep,
    float* __restrict__ out) {
  int tid = blockIdx.x * blockDim.x + threadIdx.x;  // over B*C*K/4
  const int KQ = K_DIM / 4;  // 1024
  int q = tid & (KQ - 1);
  int bc = tid >> 10;  // b*C + c
  int b = bc >> 8;     // C = 256

  int4 idx4 = ((const int4*)(keep + b * K_DIM))[q];
  const float* row = x + (size_t)bc * E_DIM;
  v4f o;
  o.x = row[idx4.x];
  o.y = row[idx4.y];
  o.z = row[idx4.z];
  o.w = row[idx4.w];
  __builtin_nontemporal_store(o, (v4f*)out + tid);
}

extern "C" void kernel_launch(void* const* d_in, const int* in_sizes, int n_in,
                              void* d_out, int out_size, void* d_ws,
                              size_t ws_size, hipStream_t stream) {
  const float* x = (const float*)d_in[0];
  const void* ec = d_in[1];
  float* out = (float*)d_out;

  unsigned* keys = (unsigned*)d_ws;                  // B*E uints (~590 KB)
  int* keep = (int*)(keys + (size_t)B_DIM * E_DIM);  // B*K ints (~256 KB)

  score_kernel<<<(B_DIM * E_DIM) / 64, 256, 0, stream>>>(x, ec, keys);
  select_kernel<<<B_DIM, SEL_T, 0, stream>>>(keys, keep);
  gather_kernel<<<(B_DIM * C_DIM * (K_DIM / 4)) / 256, 256, 0, stream>>>(
      x, keep, out);
}

// Round 2
// 278.318 us; speedup vs baseline: 1.0052x; 1.0035x over previous
//
#include <hip/hip_runtime.h>
#include <hip/hip_bf16.h>

#define B_DIM 16
#define C_DIM 256
#define E_DIM 9216
#define K_DIM 4096
#define SEL_T 512              // select block threads
#define EPT   (E_DIM / SEL_T)  // 18 keys per thread, contiguous
#define HBINS 32768            // top-15 bits (below always-set sign bit)

typedef float v4f __attribute__((ext_vector_type(4)));

// ---------------------------------------------------------------------------
// Kernel 1: score[b,e] = sum_c x[b,c,e]^2 -> sortable uint key.
// Non-negative floats: bits | 0x80000000 is order-preserving. Invalid edges
// get key 0. Double accumulation => correctly-rounded fp32 score (immune to
// reduction-order differences vs XLA at the top-K boundary).
//
// v3: wave0 additionally builds a per-mesh global histogram over the top 16
// key bits (valid keys always have bit31 set -> 32768 bins). This moves the
// expensive first radix narrowing out of the 16-block select kernel into
// this massively parallel one. 147K atomics over ~4K hot bins: negligible.
// ---------------------------------------------------------------------------
__global__ __launch_bounds__(256) void score_kernel(
    const float* __restrict__ x, const void* __restrict__ ecp,
    unsigned* __restrict__ keys, unsigned* __restrict__ hist) {
  __shared__ double part[3][64];  // waves 1..3 deposit partials

  const int lane = threadIdx.x & 63;
  const int w = threadIdx.x >> 6;           // wave id 0..3 -> c-slice
  const int blk = blockIdx.x;               // 0 .. B*E/64-1  (2304)
  const int b = blk / (E_DIM / 64);         // 144 blocks per mesh
  const int e = (blk % (E_DIM / 64)) * 64 + lane;

  const float* col =
      x + (size_t)b * C_DIM * E_DIM + (size_t)(w * 64) * E_DIM + e;

  double a0 = 0.0, a1 = 0.0;
#pragma unroll 8
  for (int c = 0; c < 64; c += 2) {
    float v0 = col[(size_t)(c + 0) * E_DIM];
    float v1 = col[(size_t)(c + 1) * E_DIM];
    a0 += (double)v0 * v0;
    a1 += (double)v1 * v1;
  }
  double s = a0 + a1;

  if (w) part[w - 1][lane] = s;
  __syncthreads();

  if (w == 0) {
    s += part[0][lane] + (part[1][lane] + part[2][lane]);

    // edges_count dtype sniff: counts are in [K, E] (fit in 16 bits), so an
    // int64 little-endian layout has zero at odd int32 positions.
    const int* p32 = (const int*)ecp;
    long long cnt =
        (p32[1] == 0) ? ((const long long*)ecp)[b] : (long long)p32[b];

    float f = (float)s;
    unsigned kk = (e < cnt) ? (__float_as_uint(f) | 0x80000000u) : 0u;
    keys[(size_t)b * E_DIM + (blk % (E_DIM / 64)) * 64 + lane] = kk;
    if (kk)  // valid keys have bit31 set; bin = top16 minus the sign bit
      atomicAdd(&hist[(unsigned)b * HBINS + ((kk >> 16) & 0x7FFFu)], 1u);
  }
}

// ---------------------------------------------------------------------------
// Block-wide exclusive scan over SEL_T threads (8 waves). Returns excl + tot.
// ---------------------------------------------------------------------------
__device__ __forceinline__ void block_scan(int val, int tid, int* wsum,
                                           int* excl, int* total) {
  int lane = tid & 63;
  int wid = tid >> 6;
  int v = val;
#pragma unroll
  for (int i = 1; i < 64; i <<= 1) {
    int t = __shfl_up(v, i, 64);
    if (lane >= i) v += t;
  }
  if (lane == 63) wsum[wid] = v;
  __syncthreads();
  int base = 0, tot = 0;
#pragma unroll
  for (int w = 0; w < SEL_T / 64; w++) {
    int s = wsum[w];
    if (w < wid) base += s;
    tot += s;
  }
  *excl = base + v - val;
  *total = tot;
  __syncthreads();
}

// ---------------------------------------------------------------------------
// Kernel 2: one block per mesh. v3 structure:
//  A) suffix-scan the mesh's 32768-bin global histogram (64 bins/thread +
//     one block scan) -> 16-bit prefix T16 and `need` (keys to take at T16).
//  B) compact candidate keys (top16==T16, expected ~tens for chi2-clustered
//     scores) into an LDS list; two 256-bin LDS-atomic radix passes over the
//     candidates give the low-16 threshold + need_eq. Replaces 4 full
//     ballot-match histogram passes (~280 instr/key -> ~20 instr/key).
//  C) compaction with ONE packed block scan, emits ascending-e order:
//     all key>T plus first need_eq key==T == sort(top_k(score,K).indices)
// ---------------------------------------------------------------------------
__global__ __launch_bounds__(SEL_T) void select_kernel(
    const unsigned* __restrict__ keys, const unsigned* __restrict__ hist,
    int* __restrict__ keep) {
  __shared__ unsigned lkeys[E_DIM];
  __shared__ unsigned short clist[E_DIM];  // candidate low-16 values
  __shared__ int hist256[256];
  __shared__ int wsum[SEL_T / 64];
  __shared__ int sh_a, sh_b;

  const int b = blockIdx.x;
  const int tid = threadIdx.x;

  // ---- Phase A: find T16 from the global per-mesh histogram ----
  const unsigned* h = hist + (size_t)b * HBINS;
  const int chunk = (SEL_T - 1) - tid;  // thread 0 owns the TOP 64 bins
  const unsigned* hc = h + chunk * (HBINS / SEL_T);
  int local = 0;
#pragma unroll
  for (int i = 0; i < (HBINS / SEL_T) / 4; i++) {
    uint4 v = ((const uint4*)hc)[i];
    local += (int)(v.x + v.y + v.z + v.w);
  }
  int excl, tot;
  block_scan(local, tid, wsum, &excl, &tot);  // excl = count of bins above
  if (excl < K_DIM && excl + local >= K_DIM) {
    int run = excl;
    for (int j = (HBINS / SEL_T) - 1; j >= 0; j--) {
      int c = (int)hc[j];
      if (run + c >= K_DIM) {  // run < K guaranteed by walk order
        sh_a = chunk * (HBINS / SEL_T) + j;  // boundary bin
        sh_b = K_DIM - run;                  // need: take this many at T16
        break;
      }
      run += c;
    }
  }
  __syncthreads();
  const unsigned T16 = 0x8000u | (unsigned)sh_a;
  int need = sh_b;

  // ---- stage keys (coalesced uint2), pull contiguous EPT into registers ----
  {
    const uint2* gk = (const uint2*)(keys + (size_t)b * E_DIM);
    uint2* lk2 = (uint2*)lkeys;
    for (int i = tid; i < E_DIM / 2; i += SEL_T) lk2[i] = gk[i];
  }
  __syncthreads();

  unsigned kreg[EPT];
  const int base_e = tid * EPT;
#pragma unroll
  for (int j = 0; j < EPT; j++) kreg[j] = lkeys[base_e + j];

  // ---- Phase B: compact candidates, select low-16 threshold ----
  int ccnt = 0;
#pragma unroll
  for (int j = 0; j < EPT; j++) ccnt += ((kreg[j] >> 16) == T16);
  int ncand;
  block_scan(ccnt, tid, wsum, &excl, &ncand);
  {
    int off = excl;
#pragma unroll
    for (int j = 0; j < EPT; j++)
      if ((kreg[j] >> 16) == T16)
        clist[off++] = (unsigned short)(kreg[j] & 0xFFFFu);
  }
  __syncthreads();

  // pass 1: bits 15..8 of the candidates
  if (tid < 256) hist256[tid] = 0;
  __syncthreads();
  for (int i = tid; i < ncand; i += SEL_T)
    atomicAdd(&hist256[clist[i] >> 8], 1);
  __syncthreads();
  int hh = (tid < 256) ? hist256[255 - tid] : 0;
  block_scan(hh, tid, wsum, &excl, &tot);
  if (tid < 256) {
    int s_incl = excl + hh;
    if (s_incl >= need && (s_incl - hh) < need) {
      sh_a = 255 - tid;             // byte1 of threshold
      sh_b = need - (s_incl - hh);  // remaining need within byte1
    }
  }
  __syncthreads();
  const int b1 = sh_a;
  need = sh_b;

  // pass 2: bits 7..0 among candidates with high byte == b1
  if (tid < 256) hist256[tid] = 0;
  __syncthreads();
  for (int i = tid; i < ncand; i += SEL_T)
    if ((int)(clist[i] >> 8) == b1) atomicAdd(&hist256[clist[i] & 255u], 1);
  __syncthreads();
  hh = (tid < 256) ? hist256[255 - tid] : 0;
  block_scan(hh, tid, wsum, &excl, &tot);
  if (tid < 256) {
    int s_incl = excl + hh;
    if (s_incl >= need && (s_incl - hh) < need) {
      sh_a = 255 - tid;
      sh_b = need - (s_incl - hh);
    }
  }
  __syncthreads();

  const unsigned T = (T16 << 16) | ((unsigned)b1 << 8) | (unsigned)sh_a;
  const int need_eq = sh_b;

  // ---- Phase C: one packed scan (gt<<16 | eq), per-thread ordered emit ----
  int gt_cnt = 0, eq_cnt = 0;
#pragma unroll
  for (int j = 0; j < EPT; j++) {
    gt_cnt += (kreg[j] > T);
    eq_cnt += (kreg[j] == T);
  }
  block_scan((gt_cnt << 16) | eq_cnt, tid, wsum, &excl, &tot);
  int gt_b = excl >> 16;
  int eq_b = excl & 0xFFFF;

  int* kout = keep + b * K_DIM;
#pragma unroll
  for (int j = 0; j < EPT; j++) {
    unsigned key = kreg[j];
    if (key > T) {
      int pos = gt_b + (eq_b < need_eq ? eq_b : need_eq);
      kout[pos] = base_e + j;
      gt_b++;
    } else if (key == T) {
      if (eq_b < need_eq) kout[gt_b + eq_b] = base_e + j;
      eq_b++;
    }
  }
}

// ---------------------------------------------------------------------------
// Kernel 3: gather. 4 outputs per thread (float4 store, int4 index load).
// Ascending indices -> high L1/L2/L3 locality on the reads. The 64 MB output
// is never re-read: non-temporal stores keep it from evicting x (151 MB)
// from the 256 MB Infinity Cache, so gather reads stay L3-served.
// ---------------------------------------------------------------------------
__global__ __launch_bounds__(256) void gather_kernel(
    const float* __restrict__ x, const int* __restrict__ keep,
    float* __restrict__ out) {
  int tid = blockIdx.x * blockDim.x + threadIdx.x;  // over B*C*K/4
  const int KQ = K_DIM / 4;  // 1024
  int q = tid & (KQ - 1);
  int bc = tid >> 10;  // b*C + c
  int b = bc >> 8;     // C = 256

  int4 idx4 = ((const int4*)(keep + b * K_DIM))[q];
  const float* row = x + (size_t)bc * E_DIM;
  v4f o;
  o.x = row[idx4.x];
  o.y = row[idx4.y];
  o.z = row[idx4.z];
  o.w = row[idx4.w];
  __builtin_nontemporal_store(o, (v4f*)out + tid);
}

extern "C" void kernel_launch(void* const* d_in, const int* in_sizes, int n_in,
                              void* d_out, int out_size, void* d_ws,
                              size_t ws_size, hipStream_t stream) {
  const float* x = (const float*)d_in[0];
  const void* ec = d_in[1];
  float* out = (float*)d_out;

  unsigned* keys = (unsigned*)d_ws;                  // B*E uints (~590 KB)
  int* keep = (int*)(keys + (size_t)B_DIM * E_DIM);  // B*K ints (~256 KB)
  unsigned* hist = (unsigned*)(keep + (size_t)B_DIM * K_DIM);  // 2 MB

  hipMemsetAsync(hist, 0, (size_t)B_DIM * HBINS * sizeof(unsigned), stream);
  score_kernel<<<(B_DIM * E_DIM) / 64, 256, 0, stream>>>(x, ec, keys, hist);
  select_kernel<<<B_DIM, SEL_T, 0, stream>>>(keys, hist, keep);
  gather_kernel<<<(B_DIM * C_DIM * (K_DIM / 4)) / 256, 256, 0, stream>>>(
      x, keep, out);
}